// Round 4
// baseline (145.437 us; speedup 1.0000x reference)
//
#include <hip/hip_runtime.h>
#include <cstdint>
#include <cstddef>

typedef __attribute__((ext_vector_type(8))) short short8;
typedef __attribute__((ext_vector_type(4))) float f32x4;

#define NB 512
#define DD 4096
#define NP 12288   // fused N' = 3*DD  (q | k | v)

// hardware packed f32x2 -> bf16x2 (RNE), 1 VALU op
__device__ __forceinline__ unsigned pk2(float a, float b) {
    unsigned r;
    asm("v_cvt_pk_bf16_f32 %0, %1, %2" : "=v"(r) : "v"(a), "v"(b));
    return r;
}

__device__ __forceinline__ void gload_lds16(const void* g, void* l) {
    __builtin_amdgcn_global_load_lds((const __attribute__((address_space(1))) void*)g,
                                     (__attribute__((address_space(3))) void*)l, 16, 0, 0);
}

// ---------------- x -> bf16 ----------------
__global__ __launch_bounds__(256) void cvt_bf16_kernel(const float* __restrict__ src,
                                                       unsigned short* __restrict__ dst,
                                                       int n8) {
    int i = blockIdx.x * 256 + threadIdx.x;
    if (i >= n8) return;
    const float4* s = (const float4*)src + (size_t)i * 2;
    float4 a = s[0], b = s[1];
    uint4 r;
    r.x = pk2(a.x, a.y);
    r.y = pk2(a.z, a.w);
    r.z = pk2(b.x, b.y);
    r.w = pk2(b.z, b.w);
    ((uint4*)dst)[i] = r;
}

// ---------------- fused qkv GEMM, split-K, BK=32 ----------------
// Pipeline: As 4-deep (gload_lds), W-regs 2-deep, Bs 2-deep.
// Raw s_barrier + lgkmcnt(0) only; NO vmcnt drain at the barrier. The
// compiler's register-dependency wait on breg (vmcnt(~6) before WRITEB)
// transitively drains the A-stage issued one iter earlier.
template<int KS>
__global__ __launch_bounds__(256, 3) void gemm_qkv_kernel(
    const unsigned short* __restrict__ xb,
    const float* __restrict__ w0, const float* __restrict__ w1, const float* __restrict__ w2,
    float* __restrict__ part)
{
    constexpr int KLEN = DD / KS;
    constexpr int NIT = KLEN / 32;
    constexpr int NWG = 96 * 4 * KS;
    constexpr int CPX = NWG / 8;

    // XCD-aware bijective swizzle: blocks sharing a W panel land on one XCD.
    const int bid = blockIdx.x;
    const int orig = (bid & 7) * CPX + (bid >> 3);
    const int nt = orig / (4 * KS);
    const int rest = orig - nt * (4 * KS);
    const int mt = rest / KS;
    const int kz = rest - mt * KS;

    const float* W = (nt < 32) ? w0 : ((nt < 64) ? w1 : w2);
    const int ntl = nt & 31;
    const float* Wbase = W + (size_t)(ntl * 128) * DD + kz * KLEN;
    const unsigned short* Abase = xb + (size_t)(mt * 128) * DD + kz * KLEN;
    float* C = part + (size_t)kz * NB * NP;

    __shared__ unsigned short As[4][128 * 32];
    __shared__ unsigned short Bs[2][128 * 32];

    const int t = threadIdx.x;
    const int l = t & 63;
    const int wv = t >> 6;
    const int wr = wv >> 1, wc = wv & 1;

    f32x4 acc[4][4];
    #pragma unroll
    for (int i = 0; i < 4; ++i)
        #pragma unroll
        for (int j = 0; j < 4; ++j)
            acc[i][j] = (f32x4){0.f, 0.f, 0.f, 0.f};

    // A staging (global_load_lds, linear dest; source chunk pre-swizzled: c ^= (row>>1)&3)
    const int arow0 = (t >> 2);
    const int acol  = (((t & 3) ^ ((t >> 3) & 3)) * 8);
    // B staging (f32 reg -> cvt_pk bf16 -> swizzled ds_write)
    const int brow = t >> 1, bh = t & 1;
    const float* wrow = Wbase + (size_t)brow * DD + bh * 16;
    const int bws = (t >> 2) & 3;
    char* const bw0 = (char*)(&Bs[0][0]) + brow * 64 + (((2 * bh) ^ bws) * 16);
    char* const bw1 = (char*)(&Bs[0][0]) + brow * 64 + (((2 * bh + 1) ^ bws) * 16);
    // fragment read chunk xor (lane-const)
    const int cx = ((l >> 4) ^ ((l >> 1) & 3));

    float4 bregA[4], bregB[4];

    #define LOADB(br, kt)  { _Pragma("unroll") for (int j = 0; j < 4; ++j) \
                               br[j] = *(const float4*)(wrow + (kt) * 32 + j * 4); }
    #define STAGEA(kt, buf) { _Pragma("unroll") for (int i = 0; i < 2; ++i) \
                               gload_lds16(Abase + (size_t)(i * 64 + arow0) * DD + (kt) * 32 + acol, \
                                           (char*)(&As[buf][0]) + i * 4096 + wv * 1024); }
    #define WRITEB(br, buf) { uint4 q0, q1; \
                              q0.x = pk2(br[0].x, br[0].y); q0.y = pk2(br[0].z, br[0].w); \
                              q0.z = pk2(br[1].x, br[1].y); q0.w = pk2(br[1].z, br[1].w); \
                              q1.x = pk2(br[2].x, br[2].y); q1.y = pk2(br[2].z, br[2].w); \
                              q1.z = pk2(br[3].x, br[3].y); q1.w = pk2(br[3].z, br[3].w); \
                              *(uint4*)(bw0 + (buf) * 8192) = q0; \
                              *(uint4*)(bw1 + (buf) * 8192) = q1; }
    #define BAR() { asm volatile("s_waitcnt lgkmcnt(0)" ::: "memory"); \
                    __builtin_amdgcn_s_barrier(); }

    // prologue: As[0],As[1] staged; W0 -> Bs[0]; W1 -> bregB
    STAGEA(0, 0);
    LOADB(bregA, 0);
    STAGEA(1, 1);
    WRITEB(bregA, 0);          // compiler waits vmcnt for bregA only
    LOADB(bregB, 1);
    BAR();

    // iter kt: compute As[kt&3] x Bs[kt&1]; stage A[kt+2]; load W[kt+2]->regs;
    //          write W[kt+1] (regs from iter kt-1) -> Bs[(kt+1)&1]
    #define ITER(kt, ac, ap, bc, bn, bwr, bld) { \
        if ((kt) + 2 < NIT) { STAGEA((kt) + 2, ap); LOADB(bld, (kt) + 2); } \
        short8 af[4], bfr[4]; \
        _Pragma("unroll") for (int fi = 0; fi < 4; ++fi) { \
            int row = wr * 64 + fi * 16 + (l & 15); \
            af[fi] = *(const short8*)((const char*)(&As[ac][0]) + row * 64 + cx * 16); \
        } \
        _Pragma("unroll") for (int fj = 0; fj < 4; ++fj) { \
            int row = wc * 64 + fj * 16 + (l & 15); \
            bfr[fj] = *(const short8*)((const char*)(&Bs[bc][0]) + row * 64 + cx * 16); \
        } \
        _Pragma("unroll") for (int fi = 0; fi < 4; ++fi) \
            _Pragma("unroll") for (int fj = 0; fj < 4; ++fj) \
                acc[fi][fj] = __builtin_amdgcn_mfma_f32_16x16x32_bf16(af[fi], bfr[fj], acc[fi][fj], 0, 0, 0); \
        if ((kt) + 1 < NIT) WRITEB(bwr, bn); \
        BAR(); \
    }

    for (int kt = 0; kt < NIT; kt += 4) {
        ITER(kt + 0, 0, 2, 0, 1, bregB, bregA);
        ITER(kt + 1, 1, 3, 1, 0, bregA, bregB);
        ITER(kt + 2, 2, 0, 0, 1, bregB, bregA);
        ITER(kt + 3, 3, 1, 1, 0, bregA, bregB);
    }
    #undef ITER
    #undef LOADB
    #undef STAGEA
    #undef WRITEB
    #undef BAR

    #pragma unroll
    for (int fi = 0; fi < 4; ++fi) {
        int rbase = mt * 128 + wr * 64 + fi * 16 + (l >> 4) * 4;
        #pragma unroll
        for (int fj = 0; fj < 4; ++fj) {
            int col = nt * 128 + wc * 64 + fj * 16 + (l & 15);
            #pragma unroll
            for (int r = 0; r < 4; ++r)
                C[(size_t)(rbase + r) * NP + col] = acc[fi][fj][r];
        }
    }
}

// ---------------- per-batch attention (f32 VALU) + split-K reduce ----------------
template<int KS>
__global__ __launch_bounds__(256) void attn_kernel(
    const float* __restrict__ part,
    const float* __restrict__ x,
    const float* __restrict__ imap,
    float* __restrict__ dout)
{
    const int b = blockIdx.x;
    const int t = threadIdx.x;
    const int l = t & 63;
    const int wv = t >> 6;

    __shared__ float sq[64 * 68];
    __shared__ float sk[64 * 68];   // reused as P with stride 65
    __shared__ float sv[64 * 68];

    const float* base0 = part + (size_t)b * NP;
    const float* base1 = part + (size_t)NB * NP + (size_t)b * NP;

    #pragma unroll
    for (int i = 0; i < 4; ++i) {
        int f4 = i * 256 + t;
        int r = f4 >> 4, c = (f4 & 15) * 4;
        float4 q4 = *(const float4*)(base0 + (size_t)f4 * 4);
        float4 k4 = *(const float4*)(base0 + DD + (size_t)f4 * 4);
        float4 v4 = *(const float4*)(base0 + 2 * DD + (size_t)f4 * 4);
        if (KS == 2) {
            float4 a4 = *(const float4*)(base1 + (size_t)f4 * 4);
            float4 b4 = *(const float4*)(base1 + DD + (size_t)f4 * 4);
            float4 c4 = *(const float4*)(base1 + 2 * DD + (size_t)f4 * 4);
            q4.x += a4.x; q4.y += a4.y; q4.z += a4.z; q4.w += a4.w;
            k4.x += b4.x; k4.y += b4.y; k4.z += b4.z; k4.w += b4.w;
            v4.x += c4.x; v4.y += c4.y; v4.z += c4.z; v4.w += c4.w;
        }
        *(float4*)(&sq[r * 68 + c]) = q4;
        *(float4*)(&sk[r * 68 + c]) = k4;
        *(float4*)(&sv[r * 68 + c]) = v4;
    }
    __syncthreads();

    float accs[16];
    #pragma unroll
    for (int i = 0; i < 16; ++i) accs[i] = 0.f;
    #pragma unroll 4
    for (int f4 = 0; f4 < 16; ++f4) {
        float4 kvv = *(const float4*)(&sk[l * 68 + f4 * 4]);
        #pragma unroll
        for (int i = 0; i < 16; ++i) {
            int h = i * 4 + wv;
            float4 qv = *(const float4*)(&sq[h * 68 + f4 * 4]);
            accs[i] = fmaf(qv.x, kvv.x, fmaf(qv.y, kvv.y, fmaf(qv.z, kvv.z, fmaf(qv.w, kvv.w, accs[i]))));
        }
    }
    __syncthreads();
    #pragma unroll
    for (int i = 0; i < 16; ++i) {
        int h = i * 4 + wv;
        float m = imap[(size_t)b * DD + h * 64 + l];
        sk[h * 65 + l] = accs[i] * 0.125f * m;
    }
    __syncthreads();

    {
        int h = t >> 2, j = t & 3;
        float e[16];
        float mx = -3.0e38f;
        #pragma unroll
        for (int q2 = 0; q2 < 16; ++q2) {
            e[q2] = sk[h * 65 + j * 16 + q2];
            mx = fmaxf(mx, e[q2]);
        }
        mx = fmaxf(mx, __shfl_xor(mx, 1));
        mx = fmaxf(mx, __shfl_xor(mx, 2));
        float s = 0.f;
        #pragma unroll
        for (int q2 = 0; q2 < 16; ++q2) { e[q2] = __expf(e[q2] - mx); s += e[q2]; }
        s += __shfl_xor(s, 1);
        s += __shfl_xor(s, 2);
        float invs = 1.0f / s;
        float* aw = dout + (size_t)NB * DD + (size_t)b * DD + h * 64 + j * 16;
        #pragma unroll
        for (int q2 = 0; q2 < 16; q2 += 4) {
            float4 w4 = {e[q2] * invs, e[q2 + 1] * invs, e[q2 + 2] * invs, e[q2 + 3] * invs};
            *(float4*)(aw + q2) = w4;
            sk[h * 65 + j * 16 + q2 + 0] = w4.x;
            sk[h * 65 + j * 16 + q2 + 1] = w4.y;
            sk[h * 65 + j * 16 + q2 + 2] = w4.z;
            sk[h * 65 + j * 16 + q2 + 3] = w4.w;
        }
    }
    __syncthreads();

    float pacc[16];
    #pragma unroll
    for (int i = 0; i < 16; ++i) pacc[i] = 0.f;
    #pragma unroll 4
    for (int g = 0; g < 64; ++g) {
        float p = sk[l * 65 + g];
        const float4* vr = (const float4*)(&sv[g * 68 + wv * 16]);
        float4 v0 = vr[0], v1 = vr[1], v2 = vr[2], v3 = vr[3];
        pacc[0]  = fmaf(p, v0.x, pacc[0]);
        pacc[1]  = fmaf(p, v0.y, pacc[1]);
        pacc[2]  = fmaf(p, v0.z, pacc[2]);
        pacc[3]  = fmaf(p, v0.w, pacc[3]);
        pacc[4]  = fmaf(p, v1.x, pacc[4]);
        pacc[5]  = fmaf(p, v1.y, pacc[5]);
        pacc[6]  = fmaf(p, v1.z, pacc[6]);
        pacc[7]  = fmaf(p, v1.w, pacc[7]);
        pacc[8]  = fmaf(p, v2.x, pacc[8]);
        pacc[9]  = fmaf(p, v2.y, pacc[9]);
        pacc[10] = fmaf(p, v2.z, pacc[10]);
        pacc[11] = fmaf(p, v2.w, pacc[11]);
        pacc[12] = fmaf(p, v3.x, pacc[12]);
        pacc[13] = fmaf(p, v3.y, pacc[13]);
        pacc[14] = fmaf(p, v3.z, pacc[14]);
        pacc[15] = fmaf(p, v3.w, pacc[15]);
    }
    const size_t ob = (size_t)b * DD + (size_t)(wv * 16) * 64 + l;
    #pragma unroll
    for (int ii = 0; ii < 16; ++ii) {
        size_t o = ob + (size_t)ii * 64;
        dout[o] = x[o] * pacc[ii];
    }
}

extern "C" void kernel_launch(void* const* d_in, const int* in_sizes, int n_in,
                              void* d_out, int out_size, void* d_ws, size_t ws_size,
                              hipStream_t stream) {
    const float* x  = (const float*)d_in[0];
    const float* im = (const float*)d_in[1];
    const float* Wq = (const float*)d_in[2];
    const float* Wk = (const float*)d_in[3];
    const float* Wv = (const float*)d_in[4];
    float* out = (float*)d_out;

    unsigned short* xb = (unsigned short*)d_ws;                        // 4 MiB
    float* part = (float*)((char*)d_ws + (size_t)NB * DD * 2);         // KS * 24 MiB

    const size_t need2 = (size_t)NB * DD * 2 + 2ull * NB * NP * 4;
    const int KS = (ws_size >= need2) ? 2 : 1;

    cvt_bf16_kernel<<<dim3((NB * DD / 8 + 255) / 256), dim3(256), 0, stream>>>(x, xb, NB * DD / 8);

    if (KS == 2) {
        gemm_qkv_kernel<2><<<dim3(96 * 4 * 2), dim3(256), 0, stream>>>(xb, Wq, Wk, Wv, part);
        attn_kernel<2><<<dim3(NB), dim3(256), 0, stream>>>(part, x, im, out);
    } else {
        gemm_qkv_kernel<1><<<dim3(96 * 4 * 1), dim3(256), 0, stream>>>(xb, Wq, Wk, Wv, part);
        attn_kernel<1><<<dim3(NB), dim3(256), 0, stream>>>(part, x, im, out);
    }
}

// Round 5
// 129.060 us; speedup vs baseline: 1.1269x; 1.1269x over previous
//
#include <hip/hip_runtime.h>
#include <cstdint>
#include <cstddef>

typedef __attribute__((ext_vector_type(8))) short short8;
typedef __attribute__((ext_vector_type(4))) float f32x4;

#define NB 512
#define DD 4096
#define NP 12288   // fused N' = 3*DD  (q | k | v)

// hardware packed f32x2 -> bf16x2 (RNE), 1 VALU op
__device__ __forceinline__ unsigned pk2(float a, float b) {
    unsigned r;
    asm("v_cvt_pk_bf16_f32 %0, %1, %2" : "=v"(r) : "v"(a), "v"(b));
    return r;
}

__device__ __forceinline__ void gload_lds16(const void* g, void* l) {
    __builtin_amdgcn_global_load_lds((const __attribute__((address_space(1))) void*)g,
                                     (__attribute__((address_space(3))) void*)l, 16, 0, 0);
}

// ---------------- x -> bf16 ----------------
__global__ __launch_bounds__(256) void cvt_bf16_kernel(const float* __restrict__ src,
                                                       unsigned short* __restrict__ dst,
                                                       int n8) {
    int i = blockIdx.x * 256 + threadIdx.x;
    if (i >= n8) return;
    const float4* s = (const float4*)src + (size_t)i * 2;
    float4 a = s[0], b = s[1];
    uint4 r;
    r.x = pk2(a.x, a.y);
    r.y = pk2(a.z, a.w);
    r.z = pk2(b.x, b.y);
    r.w = pk2(b.z, b.w);
    ((uint4*)dst)[i] = r;
}

// ---------------- fused qkv GEMM, split-K, BK=32 ----------------
// As 4-deep (gload_lds), W-regs 2-deep, Bs 2-deep; raw s_barrier + lgkmcnt(0).
// W loads COALESCED: lane group of 8 covers one row's 32 floats contiguously.
template<int KS>
__global__ __launch_bounds__(256, 3) void gemm_qkv_kernel(
    const unsigned short* __restrict__ xb,
    const float* __restrict__ w0, const float* __restrict__ w1, const float* __restrict__ w2,
    float* __restrict__ part)
{
    constexpr int KLEN = DD / KS;
    constexpr int NIT = KLEN / 32;
    constexpr int NWG = 96 * 4 * KS;
    constexpr int CPX = NWG / 8;

    // XCD-aware bijective swizzle: blocks sharing a W panel land on one XCD.
    const int bid = blockIdx.x;
    const int orig = (bid & 7) * CPX + (bid >> 3);
    const int nt = orig / (4 * KS);
    const int rest = orig - nt * (4 * KS);
    const int mt = rest / KS;
    const int kz = rest - mt * KS;

    const float* W = (nt < 32) ? w0 : ((nt < 64) ? w1 : w2);
    const int ntl = nt & 31;
    const float* Wbase = W + (size_t)(ntl * 128) * DD + kz * KLEN;
    const unsigned short* Abase = xb + (size_t)(mt * 128) * DD + kz * KLEN;
    float* C = part + (size_t)kz * NB * NP;

    __shared__ unsigned short As[4][128 * 32];
    __shared__ unsigned short Bs[2][128 * 32];

    const int t = threadIdx.x;
    const int l = t & 63;
    const int wv = t >> 6;
    const int wr = wv >> 1, wc = wv & 1;

    f32x4 acc[4][4];
    #pragma unroll
    for (int i = 0; i < 4; ++i)
        #pragma unroll
        for (int j = 0; j < 4; ++j)
            acc[i][j] = (f32x4){0.f, 0.f, 0.f, 0.f};

    // A staging (global_load_lds, linear dest; source chunk pre-swizzled: c ^= (row>>1)&3)
    const int arow0 = (t >> 2);
    const int acol  = (((t & 3) ^ ((t >> 3) & 3)) * 8);

    // B staging, COALESCED: pass p covers rows p*32..p*32+31; thread t -> row p*32+(t>>3),
    // cols (t&7)*4..+4 (8 lanes x 16B = 128B contiguous per row).
    const int brow0 = t >> 3;            // + p*32
    const int bc8   = t & 7;             // 16B chunk-half index within row
    const float* wsrc = Wbase + (size_t)brow0 * DD + bc8 * 4;
    // swizzled LDS write byte offsets (per p, compile-time-per-thread const):
    // row r: byte = r*64 + ((chunk ^ ((r>>1)&3))*16) + half*8, chunk=bc8>>1, half=bc8&1
    char* bwp[4];
    #pragma unroll
    for (int p = 0; p < 4; ++p) {
        int r = p * 32 + brow0;
        bwp[p] = (char*)(&Bs[0][0]) + r * 64 + (((bc8 >> 1) ^ ((r >> 1) & 3)) * 16) + (bc8 & 1) * 8;
    }
    // fragment read chunk xor (lane-const)
    const int cx = ((l >> 4) ^ ((l >> 1) & 3));

    float4 bregA[4], bregB[4];

    #define LOADB(br, kt)  { _Pragma("unroll") for (int p = 0; p < 4; ++p) \
                               br[p] = *(const float4*)(wsrc + (size_t)(p * 32) * DD + (kt) * 32); }
    #define STAGEA(kt, buf) { _Pragma("unroll") for (int i = 0; i < 2; ++i) \
                               gload_lds16(Abase + (size_t)(i * 64 + arow0) * DD + (kt) * 32 + acol, \
                                           (char*)(&As[buf][0]) + i * 4096 + wv * 1024); }
    #define WRITEB(br, buf) { _Pragma("unroll") for (int p = 0; p < 4; ++p) { \
                                uint2 q; \
                                q.x = pk2(br[p].x, br[p].y); \
                                q.y = pk2(br[p].z, br[p].w); \
                                *(uint2*)(bwp[p] + (buf) * 8192) = q; } }
    #define BAR() { asm volatile("s_waitcnt lgkmcnt(0)" ::: "memory"); \
                    __builtin_amdgcn_s_barrier(); }

    // prologue: As[0],As[1] staged; W0 -> Bs[0]; W1 -> bregB
    STAGEA(0, 0);
    LOADB(bregA, 0);
    STAGEA(1, 1);
    WRITEB(bregA, 0);          // compiler waits vmcnt for bregA only
    LOADB(bregB, 1);
    BAR();

    // iter kt: compute As[kt&3] x Bs[kt&1]; stage A[kt+2]; load W[kt+2]->regs;
    //          write W[kt+1] (regs from iter kt-1) -> Bs[(kt+1)&1]
    #define ITER(kt, ac, ap, bc, bn, bwr, bld) { \
        if ((kt) + 2 < NIT) { STAGEA((kt) + 2, ap); LOADB(bld, (kt) + 2); } \
        short8 af[4], bfr[4]; \
        _Pragma("unroll") for (int fi = 0; fi < 4; ++fi) { \
            int row = wr * 64 + fi * 16 + (l & 15); \
            af[fi] = *(const short8*)((const char*)(&As[ac][0]) + row * 64 + cx * 16); \
        } \
        _Pragma("unroll") for (int fj = 0; fj < 4; ++fj) { \
            int row = wc * 64 + fj * 16 + (l & 15); \
            bfr[fj] = *(const short8*)((const char*)(&Bs[bc][0]) + row * 64 + cx * 16); \
        } \
        _Pragma("unroll") for (int fi = 0; fi < 4; ++fi) \
            _Pragma("unroll") for (int fj = 0; fj < 4; ++fj) \
                acc[fi][fj] = __builtin_amdgcn_mfma_f32_16x16x32_bf16(af[fi], bfr[fj], acc[fi][fj], 0, 0, 0); \
        if ((kt) + 1 < NIT) WRITEB(bwr, bn); \
        BAR(); \
    }

    for (int kt = 0; kt < NIT; kt += 4) {
        ITER(kt + 0, 0, 2, 0, 1, bregB, bregA);
        ITER(kt + 1, 1, 3, 1, 0, bregA, bregB);
        ITER(kt + 2, 2, 0, 0, 1, bregB, bregA);
        ITER(kt + 3, 3, 1, 1, 0, bregA, bregB);
    }
    #undef ITER
    #undef LOADB
    #undef STAGEA
    #undef WRITEB
    #undef BAR

    #pragma unroll
    for (int fi = 0; fi < 4; ++fi) {
        int rbase = mt * 128 + wr * 64 + fi * 16 + (l >> 4) * 4;
        #pragma unroll
        for (int fj = 0; fj < 4; ++fj) {
            int col = nt * 128 + wc * 64 + fj * 16 + (l & 15);
            #pragma unroll
            for (int r = 0; r < 4; ++r)
                C[(size_t)(rbase + r) * NP + col] = acc[fi][fj][r];
        }
    }
}

// ---------------- per-batch attention (f32 VALU) + split-K reduce ----------------
template<int KS>
__global__ __launch_bounds__(256) void attn_kernel(
    const float* __restrict__ part,
    const float* __restrict__ x,
    const float* __restrict__ imap,
    float* __restrict__ dout)
{
    const int b = blockIdx.x;
    const int t = threadIdx.x;
    const int l = t & 63;
    const int wv = t >> 6;

    __shared__ float sq[64 * 68];
    __shared__ float sk[64 * 68];   // reused as P with stride 65
    __shared__ float sv[64 * 68];

    const float* base0 = part + (size_t)b * NP;
    const float* base1 = part + (size_t)NB * NP + (size_t)b * NP;

    #pragma unroll
    for (int i = 0; i < 4; ++i) {
        int f4 = i * 256 + t;
        int r = f4 >> 4, c = (f4 & 15) * 4;
        float4 q4 = *(const float4*)(base0 + (size_t)f4 * 4);
        float4 k4 = *(const float4*)(base0 + DD + (size_t)f4 * 4);
        float4 v4 = *(const float4*)(base0 + 2 * DD + (size_t)f4 * 4);
        if (KS == 2) {
            float4 a4 = *(const float4*)(base1 + (size_t)f4 * 4);
            float4 b4 = *(const float4*)(base1 + DD + (size_t)f4 * 4);
            float4 c4 = *(const float4*)(base1 + 2 * DD + (size_t)f4 * 4);
            q4.x += a4.x; q4.y += a4.y; q4.z += a4.z; q4.w += a4.w;
            k4.x += b4.x; k4.y += b4.y; k4.z += b4.z; k4.w += b4.w;
            v4.x += c4.x; v4.y += c4.y; v4.z += c4.z; v4.w += c4.w;
        }
        *(float4*)(&sq[r * 68 + c]) = q4;
        *(float4*)(&sk[r * 68 + c]) = k4;
        *(float4*)(&sv[r * 68 + c]) = v4;
    }
    __syncthreads();

    float accs[16];
    #pragma unroll
    for (int i = 0; i < 16; ++i) accs[i] = 0.f;
    #pragma unroll 4
    for (int f4 = 0; f4 < 16; ++f4) {
        float4 kvv = *(const float4*)(&sk[l * 68 + f4 * 4]);
        #pragma unroll
        for (int i = 0; i < 16; ++i) {
            int h = i * 4 + wv;
            float4 qv = *(const float4*)(&sq[h * 68 + f4 * 4]);
            accs[i] = fmaf(qv.x, kvv.x, fmaf(qv.y, kvv.y, fmaf(qv.z, kvv.z, fmaf(qv.w, kvv.w, accs[i]))));
        }
    }
    __syncthreads();
    #pragma unroll
    for (int i = 0; i < 16; ++i) {
        int h = i * 4 + wv;
        float m = imap[(size_t)b * DD + h * 64 + l];
        sk[h * 65 + l] = accs[i] * 0.125f * m;
    }
    __syncthreads();

    {
        int h = t >> 2, j = t & 3;
        float e[16];
        float mx = -3.0e38f;
        #pragma unroll
        for (int q2 = 0; q2 < 16; ++q2) {
            e[q2] = sk[h * 65 + j * 16 + q2];
            mx = fmaxf(mx, e[q2]);
        }
        mx = fmaxf(mx, __shfl_xor(mx, 1));
        mx = fmaxf(mx, __shfl_xor(mx, 2));
        float s = 0.f;
        #pragma unroll
        for (int q2 = 0; q2 < 16; ++q2) { e[q2] = __expf(e[q2] - mx); s += e[q2]; }
        s += __shfl_xor(s, 1);
        s += __shfl_xor(s, 2);
        float invs = 1.0f / s;
        float* aw = dout + (size_t)NB * DD + (size_t)b * DD + h * 64 + j * 16;
        #pragma unroll
        for (int q2 = 0; q2 < 16; q2 += 4) {
            float4 w4 = {e[q2] * invs, e[q2 + 1] * invs, e[q2 + 2] * invs, e[q2 + 3] * invs};
            *(float4*)(aw + q2) = w4;
            sk[h * 65 + j * 16 + q2 + 0] = w4.x;
            sk[h * 65 + j * 16 + q2 + 1] = w4.y;
            sk[h * 65 + j * 16 + q2 + 2] = w4.z;
            sk[h * 65 + j * 16 + q2 + 3] = w4.w;
        }
    }
    __syncthreads();

    float pacc[16];
    #pragma unroll
    for (int i = 0; i < 16; ++i) pacc[i] = 0.f;
    #pragma unroll 4
    for (int g = 0; g < 64; ++g) {
        float p = sk[l * 65 + g];
        const float4* vr = (const float4*)(&sv[g * 68 + wv * 16]);
        float4 v0 = vr[0], v1 = vr[1], v2 = vr[2], v3 = vr[3];
        pacc[0]  = fmaf(p, v0.x, pacc[0]);
        pacc[1]  = fmaf(p, v0.y, pacc[1]);
        pacc[2]  = fmaf(p, v0.z, pacc[2]);
        pacc[3]  = fmaf(p, v0.w, pacc[3]);
        pacc[4]  = fmaf(p, v1.x, pacc[4]);
        pacc[5]  = fmaf(p, v1.y, pacc[5]);
        pacc[6]  = fmaf(p, v1.z, pacc[6]);
        pacc[7]  = fmaf(p, v1.w, pacc[7]);
        pacc[8]  = fmaf(p, v2.x, pacc[8]);
        pacc[9]  = fmaf(p, v2.y, pacc[9]);
        pacc[10] = fmaf(p, v2.z, pacc[10]);
        pacc[11] = fmaf(p, v2.w, pacc[11]);
        pacc[12] = fmaf(p, v3.x, pacc[12]);
        pacc[13] = fmaf(p, v3.y, pacc[13]);
        pacc[14] = fmaf(p, v3.z, pacc[14]);
        pacc[15] = fmaf(p, v3.w, pacc[15]);
    }
    const size_t ob = (size_t)b * DD + (size_t)(wv * 16) * 64 + l;
    #pragma unroll
    for (int ii = 0; ii < 16; ++ii) {
        size_t o = ob + (size_t)ii * 64;
        dout[o] = x[o] * pacc[ii];
    }
}

extern "C" void kernel_launch(void* const* d_in, const int* in_sizes, int n_in,
                              void* d_out, int out_size, void* d_ws, size_t ws_size,
                              hipStream_t stream) {
    const float* x  = (const float*)d_in[0];
    const float* im = (const float*)d_in[1];
    const float* Wq = (const float*)d_in[2];
    const float* Wk = (const float*)d_in[3];
    const float* Wv = (const float*)d_in[4];
    float* out = (float*)d_out;

    unsigned short* xb = (unsigned short*)d_ws;                        // 4 MiB
    float* part = (float*)((char*)d_ws + (size_t)NB * DD * 2);         // KS * 24 MiB

    const size_t need2 = (size_t)NB * DD * 2 + 2ull * NB * NP * 4;
    const int KS = (ws_size >= need2) ? 2 : 1;

    cvt_bf16_kernel<<<dim3((NB * DD / 8 + 255) / 256), dim3(256), 0, stream>>>(x, xb, NB * DD / 8);

    if (KS == 2) {
        gemm_qkv_kernel<2><<<dim3(96 * 4 * 2), dim3(256), 0, stream>>>(xb, Wq, Wk, Wv, part);
        attn_kernel<2><<<dim3(NB), dim3(256), 0, stream>>>(part, x, im, out);
    } else {
        gemm_qkv_kernel<1><<<dim3(96 * 4 * 1), dim3(256), 0, stream>>>(xb, Wq, Wk, Wv, part);
        attn_kernel<1><<<dim3(NB), dim3(256), 0, stream>>>(part, x, im, out);
    }
}